// Round 4
// baseline (1117.806 us; speedup 1.0000x reference)
//
#include <hip/hip_runtime.h>
#include <cstdint>
#include <cstddef>

#define N_NODES_C  50000
#define N_EDGES_C  800000
#define IN_F_C     256
#define HID_C      128
#define N_GRAPHS_C 256
#define NEG_SLOPE_C 0.2f
#define SCAN_NB    ((N_NODES_C + 255) / 256)   // 196 blocks
#define N_CHUNKS   8                            // 128 feats = 8 x 16
#define AGG_NB_PER_CHUNK ((N_NODES_C + 3) / 4)  // 4 nodes (waves) per block

// ---------------------------------------------------------------------------
// CSR build: histogram of dst -> hierarchical exclusive scan -> scatter
// ---------------------------------------------------------------------------
__global__ void hist_kernel(const int* __restrict__ dst, int* __restrict__ deg, int E) {
    int e = blockIdx.x * blockDim.x + threadIdx.x;
    if (e < E) atomicAdd(&deg[dst[e]], 1);
}

__global__ __launch_bounds__(256) void scan1_kernel(const int* __restrict__ deg,
                                                    int* __restrict__ bsum, int n) {
    int i = blockIdx.x * 256 + threadIdx.x;
    int lane = threadIdx.x & 63;
    int w = threadIdx.x >> 6;
    int v = (i < n) ? deg[i] : 0;
    #pragma unroll
    for (int off = 32; off >= 1; off >>= 1) v += __shfl_xor(v, off);
    __shared__ int ws_[4];
    if (lane == 0) ws_[w] = v;
    __syncthreads();
    if (threadIdx.x == 0) bsum[blockIdx.x] = ws_[0] + ws_[1] + ws_[2] + ws_[3];
}

__global__ __launch_bounds__(256) void scan2_kernel(int* __restrict__ bsum, int nb) {
    int t = threadIdx.x;
    int lane = t & 63;
    int w = t >> 6;
    int orig = (t < nb) ? bsum[t] : 0;
    int v = orig;
    #pragma unroll
    for (int off = 1; off < 64; off <<= 1) {
        int u = __shfl_up(v, off);
        if (lane >= off) v += u;
    }
    __shared__ int wsum[4];
    if (lane == 63) wsum[w] = v;
    __syncthreads();
    int add = 0;
    for (int i = 0; i < w; ++i) add += wsum[i];
    if (t < nb) bsum[t] = v + add - orig;   // exclusive prefix
}

__global__ __launch_bounds__(256) void scan3_kernel(const int* __restrict__ deg,
                                                    const int* __restrict__ boff,
                                                    int* __restrict__ row_start,
                                                    int* __restrict__ cursor, int n) {
    int i = blockIdx.x * 256 + threadIdx.x;
    int lane = threadIdx.x & 63;
    int w = threadIdx.x >> 6;
    int d = (i < n) ? deg[i] : 0;
    int v = d;
    #pragma unroll
    for (int off = 1; off < 64; off <<= 1) {
        int u = __shfl_up(v, off);
        if (lane >= off) v += u;
    }
    __shared__ int wsum[4];
    if (lane == 63) wsum[w] = v;
    __syncthreads();
    int add = boff[blockIdx.x];
    for (int k = 0; k < w; ++k) add += wsum[k];
    int excl = v - d + add;
    if (i < n) {
        row_start[i] = excl;
        cursor[i] = excl;
        if (i == n - 1) row_start[n] = excl + d;
    }
}

__global__ void scatter_kernel(const int* __restrict__ src, const int* __restrict__ dst, int E,
                               int* __restrict__ cursor, int* __restrict__ csr_src) {
    int e = blockIdx.x * blockDim.x + threadIdx.x;
    if (e < E) {
        int pos = atomicAdd(&cursor[dst[e]], 1);
        csr_src[pos] = src[e];
    }
}

// ---------------------------------------------------------------------------
// GEMM (fp32, vector ALU): Hc = act(X) @ W written in CHUNKED layout
// Hc[chunk][node][16], chunk = col/16. Fused alpha_s/alpha_d dots.
// ---------------------------------------------------------------------------
template <int K>
__global__ __launch_bounds__(256) void gemm_alpha_kernel(
    const float* __restrict__ X, const float* __restrict__ W,
    const float* __restrict__ a_src, const float* __restrict__ a_dst,
    float* __restrict__ Hc, float* __restrict__ alpha_s, float* __restrict__ alpha_d,
    int n_rows, int do_relu)
{
    constexpr int KT = 32;
    __shared__ float Xs[64 * KT];     // 8 KiB
    __shared__ float Ws[KT * 128];    // 16 KiB

    const int t = threadIdx.x;
    const int row0 = blockIdx.x * 64;
    const int j = t & 31;             // col group: cols 4j..4j+3
    const int rg = t >> 5;            // row group: rows 8rg..8rg+7

    float acc[8][4];
    #pragma unroll
    for (int i = 0; i < 8; ++i)
        #pragma unroll
        for (int c = 0; c < 4; ++c) acc[i][c] = 0.f;

    for (int k0 = 0; k0 < K; k0 += KT) {
        __syncthreads();
        #pragma unroll
        for (int it = 0; it < 2; ++it) {
            int fi = t + it * 256;
            int r = fi >> 3;
            int c4 = (fi & 7) << 2;
            int grow = row0 + r;
            float4 v = make_float4(0.f, 0.f, 0.f, 0.f);
            if (grow < n_rows) {
                v = *reinterpret_cast<const float4*>(X + (size_t)grow * K + k0 + c4);
                if (do_relu) {
                    v.x = fmaxf(v.x, 0.f); v.y = fmaxf(v.y, 0.f);
                    v.z = fmaxf(v.z, 0.f); v.w = fmaxf(v.w, 0.f);
                }
            }
            *reinterpret_cast<float4*>(&Xs[r * KT + c4]) = v;
        }
        #pragma unroll
        for (int it = 0; it < 4; ++it) {
            int fi = t + it * 256;
            int kk = fi >> 5;
            int c4 = (fi & 31) << 2;
            float4 v = *reinterpret_cast<const float4*>(W + (size_t)(k0 + kk) * 128 + c4);
            *reinterpret_cast<float4*>(&Ws[kk * 128 + c4]) = v;
        }
        __syncthreads();
        #pragma unroll
        for (int kk = 0; kk < KT; kk += 4) {
            float4 wv[4];
            #pragma unroll
            for (int c = 0; c < 4; ++c)
                wv[c] = *reinterpret_cast<const float4*>(&Ws[(kk + c) * 128 + (j << 2)]);
            #pragma unroll
            for (int i = 0; i < 8; ++i) {
                float4 xv = *reinterpret_cast<const float4*>(&Xs[(rg * 8 + i) * KT + kk]);
                acc[i][0] = fmaf(xv.x, wv[0].x, acc[i][0]);
                acc[i][1] = fmaf(xv.x, wv[0].y, acc[i][1]);
                acc[i][2] = fmaf(xv.x, wv[0].z, acc[i][2]);
                acc[i][3] = fmaf(xv.x, wv[0].w, acc[i][3]);
                acc[i][0] = fmaf(xv.y, wv[1].x, acc[i][0]);
                acc[i][1] = fmaf(xv.y, wv[1].y, acc[i][1]);
                acc[i][2] = fmaf(xv.y, wv[1].z, acc[i][2]);
                acc[i][3] = fmaf(xv.y, wv[1].w, acc[i][3]);
                acc[i][0] = fmaf(xv.z, wv[2].x, acc[i][0]);
                acc[i][1] = fmaf(xv.z, wv[2].y, acc[i][1]);
                acc[i][2] = fmaf(xv.z, wv[2].z, acc[i][2]);
                acc[i][3] = fmaf(xv.z, wv[2].w, acc[i][3]);
                acc[i][0] = fmaf(xv.w, wv[3].x, acc[i][0]);
                acc[i][1] = fmaf(xv.w, wv[3].y, acc[i][1]);
                acc[i][2] = fmaf(xv.w, wv[3].z, acc[i][2]);
                acc[i][3] = fmaf(xv.w, wv[3].w, acc[i][3]);
            }
        }
    }

    float4 as4 = *reinterpret_cast<const float4*>(a_src + (j << 2));
    float4 ad4 = *reinterpret_cast<const float4*>(a_dst + (j << 2));
    const int chunk = j >> 2;          // col/16
    const int within = (j << 2) & 15;  // 0,4,8,12
    #pragma unroll
    for (int i = 0; i < 8; ++i) {
        int grow = row0 + rg * 8 + i;
        float s = acc[i][0] * as4.x + acc[i][1] * as4.y + acc[i][2] * as4.z + acc[i][3] * as4.w;
        float d = acc[i][0] * ad4.x + acc[i][1] * ad4.y + acc[i][2] * ad4.z + acc[i][3] * ad4.w;
        #pragma unroll
        for (int off = 16; off >= 1; off >>= 1) {
            s += __shfl_xor(s, off);
            d += __shfl_xor(d, off);
        }
        if (grow < n_rows) {
            *reinterpret_cast<float4*>(Hc + ((size_t)chunk * N_NODES_C + grow) * 16 + within) =
                make_float4(acc[i][0], acc[i][1], acc[i][2], acc[i][3]);
            if (j == 0) { alpha_s[grow] = s; alpha_d[grow] = d; }
        }
    }
}

// ---------------------------------------------------------------------------
// Pass A: per-edge unnormalized softmax weight + per-dst 1/S.
// One wave per dst node. Stores (src, w) packed 8B per edge as long long.
// ---------------------------------------------------------------------------
__global__ __launch_bounds__(256) void edge_weight_kernel(
    const float* __restrict__ alpha_s, const float* __restrict__ alpha_d,
    const int* __restrict__ row_start, const int* __restrict__ csr_src,
    long long* __restrict__ edge_sw, float* __restrict__ invS, int n_nodes)
{
    int wid = (blockIdx.x * blockDim.x + threadIdx.x) >> 6;
    int lane = threadIdx.x & 63;
    if (wid >= n_nodes) return;

    int e0 = row_start[wid], e1 = row_start[wid + 1];
    float ad = alpha_d[wid];

    float S = 0.f;
    for (int base = e0; base < e1; base += 64) {
        int e = base + lane;
        float w = 0.f;
        if (e < e1) {
            int s = csr_src[e];
            float z = alpha_s[s] + ad;
            z = (z >= 0.f) ? z : NEG_SLOPE_C * z;
            w = __expf(z);
            long long p = ((long long)__float_as_int(w) << 32) |
                          (unsigned int)s;
            __builtin_nontemporal_store(p, &edge_sw[e]);
        }
        float ws = w;
        #pragma unroll
        for (int off = 32; off >= 1; off >>= 1) ws += __shfl_xor(ws, off);
        S += ws;
    }
    if (lane == 0) invS[wid] = (e1 > e0) ? (1.f / S) : 0.f;
}

// ---------------------------------------------------------------------------
// Pass B: chunked weighted gather. chunk = blockIdx & 7 -> pins each 3.2 MB
// H-chunk to one XCD's L2 (blockIdx % 8 XCD round-robin heuristic; perf-only).
// Wave per (node, chunk): lane = 16*edge_subgroup + feature.
// ---------------------------------------------------------------------------
__global__ __launch_bounds__(256) void agg_chunk_kernel(
    const float* __restrict__ Hc, const long long* __restrict__ edge_sw,
    const int* __restrict__ row_start, const float* __restrict__ invS,
    const float* __restrict__ bias, float* __restrict__ OUT, int n_nodes)
{
    const int chunk = blockIdx.x & 7;
    const int nb = blockIdx.x >> 3;
    const int node = nb * 4 + (threadIdx.x >> 6);
    if (node >= n_nodes) return;
    const int lane = threadIdx.x & 63;
    const int f = lane & 15;      // feature within chunk
    const int g = lane >> 4;      // edge subgroup 0..3

    const int e0 = row_start[node], e1 = row_start[node + 1];
    const float* __restrict__ hb = Hc + (size_t)chunk * N_NODES_C * 16;

    float acc = 0.f;
    for (int e = e0 + g; e < e1; e += 4) {
        long long p = __builtin_nontemporal_load(&edge_sw[e]);
        int sj = (int)(p & 0xffffffffLL);
        float wj = __int_as_float((int)(p >> 32));
        acc = fmaf(wj, hb[(size_t)sj * 16 + f], acc);
    }
    // reduce the 4 edge-subgroups (lanes f, f+16, f+32, f+48)
    acc += __shfl_xor(acc, 16);
    acc += __shfl_xor(acc, 32);
    if (g == 0) {
        float r = fmaf(acc, invS[node], bias[chunk * 16 + f]);
        __builtin_nontemporal_store(r, &OUT[(size_t)node * 128 + chunk * 16 + f]);
    }
}

// ---------------------------------------------------------------------------
__global__ void graph_ranges_kernel(const int* __restrict__ batch, int n_nodes,
                                    int n_graphs, int* __restrict__ gstart) {
    int g = blockIdx.x * blockDim.x + threadIdx.x;
    if (g > n_graphs) return;
    int lo = 0, hi = n_nodes;
    while (lo < hi) {
        int mid = (lo + hi) >> 1;
        if (batch[mid] < g) lo = mid + 1; else hi = mid;
    }
    gstart[g] = lo;
}

__global__ __launch_bounds__(128) void pool_linear_kernel(
    const float* __restrict__ X, const int* __restrict__ gstart,
    const float* __restrict__ lin_w, const float* __restrict__ lin_b,
    float* __restrict__ out)
{
    int g = blockIdx.x;
    int c = threadIdx.x;   // 0..127
    int s = gstart[g], e = gstart[g + 1];
    float acc = 0.f;
    for (int i = s; i < e; ++i) acc += X[(size_t)i * 128 + c];
    float cnt = (float)(e - s);
    float pooled = acc / fmaxf(cnt, 1.0f);
    __shared__ float p[128];
    p[c] = pooled;
    __syncthreads();
    if (c < 8) {
        float o = lin_b[c];
        for (int k = 0; k < 128; ++k) o += p[k] * lin_w[k * 8 + c];
        out[g * 8 + c] = o;
    }
}

// ---------------------------------------------------------------------------
extern "C" void kernel_launch(void* const* d_in, const int* in_sizes, int n_in,
                              void* d_out, int out_size, void* d_ws, size_t ws_size,
                              hipStream_t stream)
{
    const float* x     = (const float*)d_in[0];
    const int*   ei    = (const int*)d_in[1];
    const int*   batch = (const int*)d_in[3];
    const float* W[3]   = {(const float*)d_in[4],  (const float*)d_in[8],  (const float*)d_in[12]};
    const float* asr[3] = {(const float*)d_in[5],  (const float*)d_in[9],  (const float*)d_in[13]};
    const float* adt[3] = {(const float*)d_in[6],  (const float*)d_in[10], (const float*)d_in[14]};
    const float* bia[3] = {(const float*)d_in[7],  (const float*)d_in[11], (const float*)d_in[15]};
    const float* lin_w = (const float*)d_in[16];
    const float* lin_b = (const float*)d_in[17];
    float* out = (float*)d_out;

    char* ws = (char*)d_ws;
    size_t off = 0;
    auto carve = [&](size_t bytes) {
        void* p = ws + off;
        off = (off + bytes + 255) & ~(size_t)255;
        return p;
    };
    float* bufA     = (float*)carve((size_t)N_NODES_C * 128 * 4);  // Hc (chunked)
    float* bufB     = (float*)carve((size_t)N_NODES_C * 128 * 4);  // layer out / next x
    float* alpha_s  = (float*)carve((size_t)N_NODES_C * 4);
    float* alpha_d  = (float*)carve((size_t)N_NODES_C * 4);
    float* invS     = (float*)carve((size_t)N_NODES_C * 4);
    int*   deg      = (int*)carve((size_t)N_NODES_C * 4);
    int*   row_start= (int*)carve((size_t)(N_NODES_C + 1) * 4);
    int*   cursor   = (int*)carve((size_t)N_NODES_C * 4);
    int*   csr_src  = (int*)carve((size_t)N_EDGES_C * 4);
    long long* edge_sw = (long long*)carve((size_t)N_EDGES_C * 8);
    int*   gstart   = (int*)carve((size_t)(N_GRAPHS_C + 1) * 4);
    int*   bsum     = (int*)carve((size_t)SCAN_NB * 4);

    const int* src = ei;             // edge_index[0]
    const int* dst = ei + N_EDGES_C; // edge_index[1]

    // --- CSR build (graph identical across layers) ---
    (void)hipMemsetAsync(deg, 0, (size_t)N_NODES_C * 4, stream);
    hist_kernel<<<(N_EDGES_C + 255) / 256, 256, 0, stream>>>(dst, deg, N_EDGES_C);
    scan1_kernel<<<SCAN_NB, 256, 0, stream>>>(deg, bsum, N_NODES_C);
    scan2_kernel<<<1, 256, 0, stream>>>(bsum, SCAN_NB);
    scan3_kernel<<<SCAN_NB, 256, 0, stream>>>(deg, bsum, row_start, cursor, N_NODES_C);
    scatter_kernel<<<(N_EDGES_C + 255) / 256, 256, 0, stream>>>(src, dst, N_EDGES_C,
                                                                cursor, csr_src);
    graph_ranges_kernel<<<2, 256, 0, stream>>>(batch, N_NODES_C, N_GRAPHS_C, gstart);

    const int gemm_grid = (N_NODES_C + 63) / 64;
    const int wgt_grid  = (N_NODES_C + 3) / 4;          // wave per node
    const int agg_grid  = AGG_NB_PER_CHUNK * N_CHUNKS;  // chunk = blockIdx & 7

    for (int l = 0; l < 3; ++l) {
        const float* xin = (l == 0) ? x : bufB;
        if (l == 0)
            gemm_alpha_kernel<IN_F_C><<<gemm_grid, 256, 0, stream>>>(
                xin, W[l], asr[l], adt[l], bufA, alpha_s, alpha_d, N_NODES_C, 0);
        else
            gemm_alpha_kernel<HID_C><<<gemm_grid, 256, 0, stream>>>(
                xin, W[l], asr[l], adt[l], bufA, alpha_s, alpha_d, N_NODES_C, 1);
        edge_weight_kernel<<<wgt_grid, 256, 0, stream>>>(
            alpha_s, alpha_d, row_start, csr_src, edge_sw, invS, N_NODES_C);
        agg_chunk_kernel<<<agg_grid, 256, 0, stream>>>(
            bufA, edge_sw, row_start, invS, bia[l], bufB, N_NODES_C);
    }

    // --- mean pool + linear ---
    pool_linear_kernel<<<N_GRAPHS_C, 128, 0, stream>>>(bufB, gstart, lin_w, lin_b, out);
}

// Round 5
// 835.601 us; speedup vs baseline: 1.3377x; 1.3377x over previous
//
#include <hip/hip_runtime.h>
#include <cstdint>
#include <cstddef>

#define N_NODES_C  50000
#define N_EDGES_C  800000
#define IN_F_C     256
#define HID_C      128
#define N_GRAPHS_C 256
#define NEG_SLOPE_C 0.2f
#define SCAN_NB    ((N_NODES_C + 255) / 256)   // 196 blocks
#define N_CHUNKS   8                            // 128 feats = 8 x 16
#define AGG_NB_PER_CHUNK ((N_NODES_C + 3) / 4)  // 4 nodes (waves) per block

// ---------------------------------------------------------------------------
// CSR build: histogram of dst -> hierarchical exclusive scan -> scatter
// ---------------------------------------------------------------------------
__global__ void hist_kernel(const int* __restrict__ dst, int* __restrict__ deg, int E) {
    int e = blockIdx.x * blockDim.x + threadIdx.x;
    if (e < E) atomicAdd(&deg[dst[e]], 1);
}

__global__ __launch_bounds__(256) void scan1_kernel(const int* __restrict__ deg,
                                                    int* __restrict__ bsum, int n) {
    int i = blockIdx.x * 256 + threadIdx.x;
    int lane = threadIdx.x & 63;
    int w = threadIdx.x >> 6;
    int v = (i < n) ? deg[i] : 0;
    #pragma unroll
    for (int off = 32; off >= 1; off >>= 1) v += __shfl_xor(v, off);
    __shared__ int ws_[4];
    if (lane == 0) ws_[w] = v;
    __syncthreads();
    if (threadIdx.x == 0) bsum[blockIdx.x] = ws_[0] + ws_[1] + ws_[2] + ws_[3];
}

__global__ __launch_bounds__(256) void scan2_kernel(int* __restrict__ bsum, int nb) {
    int t = threadIdx.x;
    int lane = t & 63;
    int w = t >> 6;
    int orig = (t < nb) ? bsum[t] : 0;
    int v = orig;
    #pragma unroll
    for (int off = 1; off < 64; off <<= 1) {
        int u = __shfl_up(v, off);
        if (lane >= off) v += u;
    }
    __shared__ int wsum[4];
    if (lane == 63) wsum[w] = v;
    __syncthreads();
    int add = 0;
    for (int i = 0; i < w; ++i) add += wsum[i];
    if (t < nb) bsum[t] = v + add - orig;   // exclusive prefix
}

__global__ __launch_bounds__(256) void scan3_kernel(const int* __restrict__ deg,
                                                    const int* __restrict__ boff,
                                                    int* __restrict__ row_start,
                                                    int* __restrict__ cursor, int n) {
    int i = blockIdx.x * 256 + threadIdx.x;
    int lane = threadIdx.x & 63;
    int w = threadIdx.x >> 6;
    int d = (i < n) ? deg[i] : 0;
    int v = d;
    #pragma unroll
    for (int off = 1; off < 64; off <<= 1) {
        int u = __shfl_up(v, off);
        if (lane >= off) v += u;
    }
    __shared__ int wsum[4];
    if (lane == 63) wsum[w] = v;
    __syncthreads();
    int add = boff[blockIdx.x];
    for (int k = 0; k < w; ++k) add += wsum[k];
    int excl = v - d + add;
    if (i < n) {
        row_start[i] = excl;
        cursor[i] = excl;
        if (i == n - 1) row_start[n] = excl + d;
    }
}

__global__ void scatter_kernel(const int* __restrict__ src, const int* __restrict__ dst, int E,
                               int* __restrict__ cursor, int* __restrict__ csr_src) {
    int e = blockIdx.x * blockDim.x + threadIdx.x;
    if (e < E) {
        int pos = atomicAdd(&cursor[dst[e]], 1);
        csr_src[pos] = src[e];
    }
}

// ---------------------------------------------------------------------------
// GEMM (fp32, vector ALU): Hc = act(X) @ W written in CHUNKED layout
// Hc[chunk][node][16], chunk = col/16. Fused alpha_s/alpha_d dots.
// ---------------------------------------------------------------------------
template <int K>
__global__ __launch_bounds__(256) void gemm_alpha_kernel(
    const float* __restrict__ X, const float* __restrict__ W,
    const float* __restrict__ a_src, const float* __restrict__ a_dst,
    float* __restrict__ Hc, float* __restrict__ alpha_s, float* __restrict__ alpha_d,
    int n_rows, int do_relu)
{
    constexpr int KT = 32;
    __shared__ float Xs[64 * KT];     // 8 KiB
    __shared__ float Ws[KT * 128];    // 16 KiB

    const int t = threadIdx.x;
    const int row0 = blockIdx.x * 64;
    const int j = t & 31;             // col group: cols 4j..4j+3
    const int rg = t >> 5;            // row group: rows 8rg..8rg+7

    float acc[8][4];
    #pragma unroll
    for (int i = 0; i < 8; ++i)
        #pragma unroll
        for (int c = 0; c < 4; ++c) acc[i][c] = 0.f;

    for (int k0 = 0; k0 < K; k0 += KT) {
        __syncthreads();
        #pragma unroll
        for (int it = 0; it < 2; ++it) {
            int fi = t + it * 256;
            int r = fi >> 3;
            int c4 = (fi & 7) << 2;
            int grow = row0 + r;
            float4 v = make_float4(0.f, 0.f, 0.f, 0.f);
            if (grow < n_rows) {
                v = *reinterpret_cast<const float4*>(X + (size_t)grow * K + k0 + c4);
                if (do_relu) {
                    v.x = fmaxf(v.x, 0.f); v.y = fmaxf(v.y, 0.f);
                    v.z = fmaxf(v.z, 0.f); v.w = fmaxf(v.w, 0.f);
                }
            }
            *reinterpret_cast<float4*>(&Xs[r * KT + c4]) = v;
        }
        #pragma unroll
        for (int it = 0; it < 4; ++it) {
            int fi = t + it * 256;
            int kk = fi >> 5;
            int c4 = (fi & 31) << 2;
            float4 v = *reinterpret_cast<const float4*>(W + (size_t)(k0 + kk) * 128 + c4);
            *reinterpret_cast<float4*>(&Ws[kk * 128 + c4]) = v;
        }
        __syncthreads();
        #pragma unroll
        for (int kk = 0; kk < KT; kk += 4) {
            float4 wv[4];
            #pragma unroll
            for (int c = 0; c < 4; ++c)
                wv[c] = *reinterpret_cast<const float4*>(&Ws[(kk + c) * 128 + (j << 2)]);
            #pragma unroll
            for (int i = 0; i < 8; ++i) {
                float4 xv = *reinterpret_cast<const float4*>(&Xs[(rg * 8 + i) * KT + kk]);
                acc[i][0] = fmaf(xv.x, wv[0].x, acc[i][0]);
                acc[i][1] = fmaf(xv.x, wv[0].y, acc[i][1]);
                acc[i][2] = fmaf(xv.x, wv[0].z, acc[i][2]);
                acc[i][3] = fmaf(xv.x, wv[0].w, acc[i][3]);
                acc[i][0] = fmaf(xv.y, wv[1].x, acc[i][0]);
                acc[i][1] = fmaf(xv.y, wv[1].y, acc[i][1]);
                acc[i][2] = fmaf(xv.y, wv[1].z, acc[i][2]);
                acc[i][3] = fmaf(xv.y, wv[1].w, acc[i][3]);
                acc[i][0] = fmaf(xv.z, wv[2].x, acc[i][0]);
                acc[i][1] = fmaf(xv.z, wv[2].y, acc[i][1]);
                acc[i][2] = fmaf(xv.z, wv[2].z, acc[i][2]);
                acc[i][3] = fmaf(xv.z, wv[2].w, acc[i][3]);
                acc[i][0] = fmaf(xv.w, wv[3].x, acc[i][0]);
                acc[i][1] = fmaf(xv.w, wv[3].y, acc[i][1]);
                acc[i][2] = fmaf(xv.w, wv[3].z, acc[i][2]);
                acc[i][3] = fmaf(xv.w, wv[3].w, acc[i][3]);
            }
        }
    }

    float4 as4 = *reinterpret_cast<const float4*>(a_src + (j << 2));
    float4 ad4 = *reinterpret_cast<const float4*>(a_dst + (j << 2));
    const int chunk = j >> 2;          // col/16
    const int within = (j << 2) & 15;  // 0,4,8,12
    #pragma unroll
    for (int i = 0; i < 8; ++i) {
        int grow = row0 + rg * 8 + i;
        float s = acc[i][0] * as4.x + acc[i][1] * as4.y + acc[i][2] * as4.z + acc[i][3] * as4.w;
        float d = acc[i][0] * ad4.x + acc[i][1] * ad4.y + acc[i][2] * ad4.z + acc[i][3] * ad4.w;
        #pragma unroll
        for (int off = 16; off >= 1; off >>= 1) {
            s += __shfl_xor(s, off);
            d += __shfl_xor(d, off);
        }
        if (grow < n_rows) {
            *reinterpret_cast<float4*>(Hc + ((size_t)chunk * N_NODES_C + grow) * 16 + within) =
                make_float4(acc[i][0], acc[i][1], acc[i][2], acc[i][3]);
            if (j == 0) { alpha_s[grow] = s; alpha_d[grow] = d; }
        }
    }
}

// ---------------------------------------------------------------------------
// Pass A: per-edge unnormalized softmax weight + per-dst 1/S.
// One wave per dst node. Stores (src, w) packed 8B per edge as long long.
// NO nontemporal: edge_sw is re-read 8x by agg_chunk -> let it live in L2.
// ---------------------------------------------------------------------------
__global__ __launch_bounds__(256) void edge_weight_kernel(
    const float* __restrict__ alpha_s, const float* __restrict__ alpha_d,
    const int* __restrict__ row_start, const int* __restrict__ csr_src,
    long long* __restrict__ edge_sw, float* __restrict__ invS, int n_nodes)
{
    int wid = (blockIdx.x * blockDim.x + threadIdx.x) >> 6;
    int lane = threadIdx.x & 63;
    if (wid >= n_nodes) return;

    int e0 = row_start[wid], e1 = row_start[wid + 1];
    float ad = alpha_d[wid];

    float S = 0.f;
    for (int base = e0; base < e1; base += 64) {
        int e = base + lane;
        float w = 0.f;
        if (e < e1) {
            int s = csr_src[e];
            float z = alpha_s[s] + ad;
            z = (z >= 0.f) ? z : NEG_SLOPE_C * z;
            w = __expf(z);
            long long p = ((long long)__float_as_int(w) << 32) |
                          (unsigned int)s;
            edge_sw[e] = p;
        }
        float ws = w;
        #pragma unroll
        for (int off = 32; off >= 1; off >>= 1) ws += __shfl_xor(ws, off);
        S += ws;
    }
    if (lane == 0) invS[wid] = (e1 > e0) ? (1.f / S) : 0.f;
}

// ---------------------------------------------------------------------------
// Pass B: chunked weighted gather. chunk = blockIdx & 7 -> pins each 3.2 MB
// H-chunk to one XCD's L2 (blockIdx % 8 XCD round-robin heuristic; perf-only).
// Wave per (node, chunk): lane = 16*edge_subgroup + feature.
// Edge loop unrolled x4 with predicated clamped loads: 16 edges per latency
// round-trip (4 independent edge_sw loads, then 4 independent gathers).
// ---------------------------------------------------------------------------
__global__ __launch_bounds__(256) void agg_chunk_kernel(
    const float* __restrict__ Hc, const long long* __restrict__ edge_sw,
    const int* __restrict__ row_start, const float* __restrict__ invS,
    const float* __restrict__ bias, float* __restrict__ OUT, int n_nodes)
{
    const int chunk = blockIdx.x & 7;
    const int nb = blockIdx.x >> 3;
    const int node = nb * 4 + (threadIdx.x >> 6);
    if (node >= n_nodes) return;
    const int lane = threadIdx.x & 63;
    const int f = lane & 15;      // feature within chunk
    const int g = lane >> 4;      // edge subgroup 0..3
    const int fidx = chunk * 16 + f;

    const int e0 = row_start[node], e1 = row_start[node + 1];
    if (e0 == e1) {               // isolated node: out = bias
        if (g == 0)
            __builtin_nontemporal_store(bias[fidx], &OUT[(size_t)node * 128 + fidx]);
        return;
    }
    const float* __restrict__ hb = Hc + (size_t)chunk * N_NODES_C * 16;

    float a0 = 0.f, a1 = 0.f, a2 = 0.f, a3 = 0.f;
    for (int base = e0 + g; base < e1; base += 16) {
        const int eb = base + 4, ec = base + 8, ed = base + 12;
        // clamp OOB slots to a valid address; weight predicated to 0
        const int ca = base;
        const int cb = (eb < e1) ? eb : e0;
        const int cc = (ec < e1) ? ec : e0;
        const int cd = (ed < e1) ? ed : e0;
        const long long pa = edge_sw[ca];
        const long long pb = edge_sw[cb];
        const long long pc = edge_sw[cc];
        const long long pd = edge_sw[cd];
        const float wa = __int_as_float((int)(pa >> 32));
        const float wb = (eb < e1) ? __int_as_float((int)(pb >> 32)) : 0.f;
        const float wc = (ec < e1) ? __int_as_float((int)(pc >> 32)) : 0.f;
        const float wd = (ed < e1) ? __int_as_float((int)(pd >> 32)) : 0.f;
        const float va = hb[(size_t)(unsigned)(int)pa * 16 + f];
        const float vb = hb[(size_t)(unsigned)(int)pb * 16 + f];
        const float vc = hb[(size_t)(unsigned)(int)pc * 16 + f];
        const float vd = hb[(size_t)(unsigned)(int)pd * 16 + f];
        a0 = fmaf(wa, va, a0);
        a1 = fmaf(wb, vb, a1);
        a2 = fmaf(wc, vc, a2);
        a3 = fmaf(wd, vd, a3);
    }
    float acc = (a0 + a1) + (a2 + a3);
    // reduce the 4 edge-subgroups (lanes f, f+16, f+32, f+48)
    acc += __shfl_xor(acc, 16);
    acc += __shfl_xor(acc, 32);
    if (g == 0) {
        float r = fmaf(acc, invS[node], bias[fidx]);
        __builtin_nontemporal_store(r, &OUT[(size_t)node * 128 + fidx]);
    }
}

// ---------------------------------------------------------------------------
__global__ void graph_ranges_kernel(const int* __restrict__ batch, int n_nodes,
                                    int n_graphs, int* __restrict__ gstart) {
    int g = blockIdx.x * blockDim.x + threadIdx.x;
    if (g > n_graphs) return;
    int lo = 0, hi = n_nodes;
    while (lo < hi) {
        int mid = (lo + hi) >> 1;
        if (batch[mid] < g) lo = mid + 1; else hi = mid;
    }
    gstart[g] = lo;
}

__global__ __launch_bounds__(128) void pool_linear_kernel(
    const float* __restrict__ X, const int* __restrict__ gstart,
    const float* __restrict__ lin_w, const float* __restrict__ lin_b,
    float* __restrict__ out)
{
    int g = blockIdx.x;
    int c = threadIdx.x;   // 0..127
    int s = gstart[g], e = gstart[g + 1];
    float acc = 0.f;
    for (int i = s; i < e; ++i) acc += X[(size_t)i * 128 + c];
    float cnt = (float)(e - s);
    float pooled = acc / fmaxf(cnt, 1.0f);
    __shared__ float p[128];
    p[c] = pooled;
    __syncthreads();
    if (c < 8) {
        float o = lin_b[c];
        for (int k = 0; k < 128; ++k) o += p[k] * lin_w[k * 8 + c];
        out[g * 8 + c] = o;
    }
}

// ---------------------------------------------------------------------------
extern "C" void kernel_launch(void* const* d_in, const int* in_sizes, int n_in,
                              void* d_out, int out_size, void* d_ws, size_t ws_size,
                              hipStream_t stream)
{
    const float* x     = (const float*)d_in[0];
    const int*   ei    = (const int*)d_in[1];
    const int*   batch = (const int*)d_in[3];
    const float* W[3]   = {(const float*)d_in[4],  (const float*)d_in[8],  (const float*)d_in[12]};
    const float* asr[3] = {(const float*)d_in[5],  (const float*)d_in[9],  (const float*)d_in[13]};
    const float* adt[3] = {(const float*)d_in[6],  (const float*)d_in[10], (const float*)d_in[14]};
    const float* bia[3] = {(const float*)d_in[7],  (const float*)d_in[11], (const float*)d_in[15]};
    const float* lin_w = (const float*)d_in[16];
    const float* lin_b = (const float*)d_in[17];
    float* out = (float*)d_out;

    char* ws = (char*)d_ws;
    size_t off = 0;
    auto carve = [&](size_t bytes) {
        void* p = ws + off;
        off = (off + bytes + 255) & ~(size_t)255;
        return p;
    };
    float* bufA     = (float*)carve((size_t)N_NODES_C * 128 * 4);  // Hc (chunked)
    float* bufB     = (float*)carve((size_t)N_NODES_C * 128 * 4);  // layer out / next x
    float* alpha_s  = (float*)carve((size_t)N_NODES_C * 4);
    float* alpha_d  = (float*)carve((size_t)N_NODES_C * 4);
    float* invS     = (float*)carve((size_t)N_NODES_C * 4);
    int*   deg      = (int*)carve((size_t)N_NODES_C * 4);
    int*   row_start= (int*)carve((size_t)(N_NODES_C + 1) * 4);
    int*   cursor   = (int*)carve((size_t)N_NODES_C * 4);
    int*   csr_src  = (int*)carve((size_t)N_EDGES_C * 4);
    long long* edge_sw = (long long*)carve((size_t)N_EDGES_C * 8);
    int*   gstart   = (int*)carve((size_t)(N_GRAPHS_C + 1) * 4);
    int*   bsum     = (int*)carve((size_t)SCAN_NB * 4);

    const int* src = ei;             // edge_index[0]
    const int* dst = ei + N_EDGES_C; // edge_index[1]

    // --- CSR build (graph identical across layers) ---
    (void)hipMemsetAsync(deg, 0, (size_t)N_NODES_C * 4, stream);
    hist_kernel<<<(N_EDGES_C + 255) / 256, 256, 0, stream>>>(dst, deg, N_EDGES_C);
    scan1_kernel<<<SCAN_NB, 256, 0, stream>>>(deg, bsum, N_NODES_C);
    scan2_kernel<<<1, 256, 0, stream>>>(bsum, SCAN_NB);
    scan3_kernel<<<SCAN_NB, 256, 0, stream>>>(deg, bsum, row_start, cursor, N_NODES_C);
    scatter_kernel<<<(N_EDGES_C + 255) / 256, 256, 0, stream>>>(src, dst, N_EDGES_C,
                                                                cursor, csr_src);
    graph_ranges_kernel<<<2, 256, 0, stream>>>(batch, N_NODES_C, N_GRAPHS_C, gstart);

    const int gemm_grid = (N_NODES_C + 63) / 64;
    const int wgt_grid  = (N_NODES_C + 3) / 4;          // wave per node
    const int agg_grid  = AGG_NB_PER_CHUNK * N_CHUNKS;  // chunk = blockIdx & 7

    for (int l = 0; l < 3; ++l) {
        const float* xin = (l == 0) ? x : bufB;
        if (l == 0)
            gemm_alpha_kernel<IN_F_C><<<gemm_grid, 256, 0, stream>>>(
                xin, W[l], asr[l], adt[l], bufA, alpha_s, alpha_d, N_NODES_C, 0);
        else
            gemm_alpha_kernel<HID_C><<<gemm_grid, 256, 0, stream>>>(
                xin, W[l], asr[l], adt[l], bufA, alpha_s, alpha_d, N_NODES_C, 1);
        edge_weight_kernel<<<wgt_grid, 256, 0, stream>>>(
            alpha_s, alpha_d, row_start, csr_src, edge_sw, invS, N_NODES_C);
        agg_chunk_kernel<<<agg_grid, 256, 0, stream>>>(
            bufA, edge_sw, row_start, invS, bia[l], bufB, N_NODES_C);
    }

    // --- mean pool + linear ---
    pool_linear_kernel<<<N_GRAPHS_C, 128, 0, stream>>>(bufB, gstart, lin_w, lin_b, out);
}

// Round 6
// 722.680 us; speedup vs baseline: 1.5468x; 1.1563x over previous
//
#include <hip/hip_runtime.h>
#include <cstdint>
#include <cstddef>

#define N_NODES_C  50000
#define N_EDGES_C  800000
#define IN_F_C     256
#define HID_C      128
#define N_GRAPHS_C 256
#define NEG_SLOPE_C 0.2f
#define SCAN_NB    ((N_NODES_C + 255) / 256)   // 196 blocks
#define N_CHUNKS   8                            // 128 feats = 8 x 16
// 16 nodes per block (4 waves x 4 nodes); 50000/16 = 3125 exactly
#define AGG_NODE_BLOCKS (N_NODES_C / 16)

// ---------------------------------------------------------------------------
// CSR build: histogram of dst -> hierarchical exclusive scan -> scatter
// ---------------------------------------------------------------------------
__global__ void hist_kernel(const int* __restrict__ dst, int* __restrict__ deg, int E) {
    int e = blockIdx.x * blockDim.x + threadIdx.x;
    if (e < E) atomicAdd(&deg[dst[e]], 1);
}

__global__ __launch_bounds__(256) void scan1_kernel(const int* __restrict__ deg,
                                                    int* __restrict__ bsum, int n) {
    int i = blockIdx.x * 256 + threadIdx.x;
    int lane = threadIdx.x & 63;
    int w = threadIdx.x >> 6;
    int v = (i < n) ? deg[i] : 0;
    #pragma unroll
    for (int off = 32; off >= 1; off >>= 1) v += __shfl_xor(v, off);
    __shared__ int ws_[4];
    if (lane == 0) ws_[w] = v;
    __syncthreads();
    if (threadIdx.x == 0) bsum[blockIdx.x] = ws_[0] + ws_[1] + ws_[2] + ws_[3];
}

__global__ __launch_bounds__(256) void scan2_kernel(int* __restrict__ bsum, int nb) {
    int t = threadIdx.x;
    int lane = t & 63;
    int w = t >> 6;
    int orig = (t < nb) ? bsum[t] : 0;
    int v = orig;
    #pragma unroll
    for (int off = 1; off < 64; off <<= 1) {
        int u = __shfl_up(v, off);
        if (lane >= off) v += u;
    }
    __shared__ int wsum[4];
    if (lane == 63) wsum[w] = v;
    __syncthreads();
    int add = 0;
    for (int i = 0; i < w; ++i) add += wsum[i];
    if (t < nb) bsum[t] = v + add - orig;   // exclusive prefix
}

__global__ __launch_bounds__(256) void scan3_kernel(const int* __restrict__ deg,
                                                    const int* __restrict__ boff,
                                                    int* __restrict__ row_start,
                                                    int* __restrict__ cursor, int n) {
    int i = blockIdx.x * 256 + threadIdx.x;
    int lane = threadIdx.x & 63;
    int w = threadIdx.x >> 6;
    int d = (i < n) ? deg[i] : 0;
    int v = d;
    #pragma unroll
    for (int off = 1; off < 64; off <<= 1) {
        int u = __shfl_up(v, off);
        if (lane >= off) v += u;
    }
    __shared__ int wsum[4];
    if (lane == 63) wsum[w] = v;
    __syncthreads();
    int add = boff[blockIdx.x];
    for (int k = 0; k < w; ++k) add += wsum[k];
    int excl = v - d + add;
    if (i < n) {
        row_start[i] = excl;
        cursor[i] = excl;
        if (i == n - 1) row_start[n] = excl + d;
    }
}

__global__ void scatter_kernel(const int* __restrict__ src, const int* __restrict__ dst, int E,
                               int* __restrict__ cursor, int* __restrict__ csr_src) {
    int e = blockIdx.x * blockDim.x + threadIdx.x;
    if (e < E) {
        int pos = atomicAdd(&cursor[dst[e]], 1);
        csr_src[pos] = src[e];
    }
}

// ---------------------------------------------------------------------------
// GEMM (fp32, vector ALU): Hc = act(X) @ W written in CHUNKED layout
// Hc[chunk][node][16], chunk = col/16. Fused alpha_s/alpha_d dots.
// ---------------------------------------------------------------------------
template <int K>
__global__ __launch_bounds__(256) void gemm_alpha_kernel(
    const float* __restrict__ X, const float* __restrict__ W,
    const float* __restrict__ a_src, const float* __restrict__ a_dst,
    float* __restrict__ Hc, float* __restrict__ alpha_s, float* __restrict__ alpha_d,
    int n_rows, int do_relu)
{
    constexpr int KT = 32;
    __shared__ float Xs[64 * KT];     // 8 KiB
    __shared__ float Ws[KT * 128];    // 16 KiB

    const int t = threadIdx.x;
    const int row0 = blockIdx.x * 64;
    const int j = t & 31;             // col group: cols 4j..4j+3
    const int rg = t >> 5;            // row group: rows 8rg..8rg+7

    float acc[8][4];
    #pragma unroll
    for (int i = 0; i < 8; ++i)
        #pragma unroll
        for (int c = 0; c < 4; ++c) acc[i][c] = 0.f;

    for (int k0 = 0; k0 < K; k0 += KT) {
        __syncthreads();
        #pragma unroll
        for (int it = 0; it < 2; ++it) {
            int fi = t + it * 256;
            int r = fi >> 3;
            int c4 = (fi & 7) << 2;
            int grow = row0 + r;
            float4 v = make_float4(0.f, 0.f, 0.f, 0.f);
            if (grow < n_rows) {
                v = *reinterpret_cast<const float4*>(X + (size_t)grow * K + k0 + c4);
                if (do_relu) {
                    v.x = fmaxf(v.x, 0.f); v.y = fmaxf(v.y, 0.f);
                    v.z = fmaxf(v.z, 0.f); v.w = fmaxf(v.w, 0.f);
                }
            }
            *reinterpret_cast<float4*>(&Xs[r * KT + c4]) = v;
        }
        #pragma unroll
        for (int it = 0; it < 4; ++it) {
            int fi = t + it * 256;
            int kk = fi >> 5;
            int c4 = (fi & 31) << 2;
            float4 v = *reinterpret_cast<const float4*>(W + (size_t)(k0 + kk) * 128 + c4);
            *reinterpret_cast<float4*>(&Ws[kk * 128 + c4]) = v;
        }
        __syncthreads();
        #pragma unroll
        for (int kk = 0; kk < KT; kk += 4) {
            float4 wv[4];
            #pragma unroll
            for (int c = 0; c < 4; ++c)
                wv[c] = *reinterpret_cast<const float4*>(&Ws[(kk + c) * 128 + (j << 2)]);
            #pragma unroll
            for (int i = 0; i < 8; ++i) {
                float4 xv = *reinterpret_cast<const float4*>(&Xs[(rg * 8 + i) * KT + kk]);
                acc[i][0] = fmaf(xv.x, wv[0].x, acc[i][0]);
                acc[i][1] = fmaf(xv.x, wv[0].y, acc[i][1]);
                acc[i][2] = fmaf(xv.x, wv[0].z, acc[i][2]);
                acc[i][3] = fmaf(xv.x, wv[0].w, acc[i][3]);
                acc[i][0] = fmaf(xv.y, wv[1].x, acc[i][0]);
                acc[i][1] = fmaf(xv.y, wv[1].y, acc[i][1]);
                acc[i][2] = fmaf(xv.y, wv[1].z, acc[i][2]);
                acc[i][3] = fmaf(xv.y, wv[1].w, acc[i][3]);
                acc[i][0] = fmaf(xv.z, wv[2].x, acc[i][0]);
                acc[i][1] = fmaf(xv.z, wv[2].y, acc[i][1]);
                acc[i][2] = fmaf(xv.z, wv[2].z, acc[i][2]);
                acc[i][3] = fmaf(xv.z, wv[2].w, acc[i][3]);
                acc[i][0] = fmaf(xv.w, wv[3].x, acc[i][0]);
                acc[i][1] = fmaf(xv.w, wv[3].y, acc[i][1]);
                acc[i][2] = fmaf(xv.w, wv[3].z, acc[i][2]);
                acc[i][3] = fmaf(xv.w, wv[3].w, acc[i][3]);
            }
        }
    }

    float4 as4 = *reinterpret_cast<const float4*>(a_src + (j << 2));
    float4 ad4 = *reinterpret_cast<const float4*>(a_dst + (j << 2));
    const int chunk = j >> 2;          // col/16
    const int within = (j << 2) & 15;  // 0,4,8,12
    #pragma unroll
    for (int i = 0; i < 8; ++i) {
        int grow = row0 + rg * 8 + i;
        float s = acc[i][0] * as4.x + acc[i][1] * as4.y + acc[i][2] * as4.z + acc[i][3] * as4.w;
        float d = acc[i][0] * ad4.x + acc[i][1] * ad4.y + acc[i][2] * ad4.z + acc[i][3] * ad4.w;
        #pragma unroll
        for (int off = 16; off >= 1; off >>= 1) {
            s += __shfl_xor(s, off);
            d += __shfl_xor(d, off);
        }
        if (grow < n_rows) {
            *reinterpret_cast<float4*>(Hc + ((size_t)chunk * N_NODES_C + grow) * 16 + within) =
                make_float4(acc[i][0], acc[i][1], acc[i][2], acc[i][3]);
            if (j == 0) { alpha_s[grow] = s; alpha_d[grow] = d; }
        }
    }
}

// ---------------------------------------------------------------------------
// Pass A: per-edge unnormalized softmax weight + per-dst 1/S.
// One wave per dst node. Stores (src, w) packed 8B per edge as long long.
// NO nontemporal: edge_sw is re-read 8x by agg_chunk -> let it live in L2.
// ---------------------------------------------------------------------------
__global__ __launch_bounds__(256) void edge_weight_kernel(
    const float* __restrict__ alpha_s, const float* __restrict__ alpha_d,
    const int* __restrict__ row_start, const int* __restrict__ csr_src,
    long long* __restrict__ edge_sw, float* __restrict__ invS, int n_nodes)
{
    int wid = (blockIdx.x * blockDim.x + threadIdx.x) >> 6;
    int lane = threadIdx.x & 63;
    if (wid >= n_nodes) return;

    int e0 = row_start[wid], e1 = row_start[wid + 1];
    float ad = alpha_d[wid];

    float S = 0.f;
    for (int base = e0; base < e1; base += 64) {
        int e = base + lane;
        float w = 0.f;
        if (e < e1) {
            int s = csr_src[e];
            float z = alpha_s[s] + ad;
            z = (z >= 0.f) ? z : NEG_SLOPE_C * z;
            w = __expf(z);
            long long p = ((long long)__float_as_int(w) << 32) |
                          (unsigned int)s;
            edge_sw[e] = p;
        }
        float ws = w;
        #pragma unroll
        for (int off = 32; off >= 1; off >>= 1) ws += __shfl_xor(ws, off);
        S += ws;
    }
    if (lane == 0) invS[wid] = (e1 > e0) ? (1.f / S) : 0.f;
}

// ---------------------------------------------------------------------------
// Pass B: chunked weighted gather. chunk = blockIdx & 7 pins each 3.2 MB
// H-chunk to one XCD's L2 (perf heuristic only).
// Wave layout: lane = eslot*4 + fq. One wave handles 4 consecutive nodes
// serially; per edge-loop iteration the wave covers 16 edges, each lane
// gathering float4 (16 B) -> 1 KB per gather instruction.
// 50000 nodes = 3125 blocks x 16 nodes exactly: no bounds checks.
// ---------------------------------------------------------------------------
__global__ __launch_bounds__(256) void agg_chunk_kernel(
    const float* __restrict__ Hc, const long long* __restrict__ edge_sw,
    const int* __restrict__ row_start, const float* __restrict__ invS,
    const float* __restrict__ bias, float* __restrict__ OUT)
{
    const int chunk = blockIdx.x & 7;
    const int node0 = (blockIdx.x >> 3) * 16 + (threadIdx.x >> 6) * 4;
    const int lane  = threadIdx.x & 63;
    const int eslot = lane >> 2;        // 0..15: edge slot
    const int fq    = lane & 3;         // feature quad: feats 4fq..4fq+3

    const float* __restrict__ hb = Hc + (size_t)chunk * N_NODES_C * 16;
    const float4 b4 = *reinterpret_cast<const float4*>(bias + chunk * 16 + fq * 4);

    #pragma unroll
    for (int ni = 0; ni < 4; ++ni) {
        const int node = node0 + ni;
        const int e0 = row_start[node], e1 = row_start[node + 1];
        float4 acc = make_float4(0.f, 0.f, 0.f, 0.f);
        for (int base = e0; base < e1; base += 16) {
            const int e = base + eslot;
            const int ce = (e < e1) ? e : e0;           // clamp OOB to valid addr
            const long long p = edge_sw[ce];
            const float w = (e < e1) ? __int_as_float((int)(p >> 32)) : 0.f;
            const int sj = (int)p;                      // low 32 bits = src id
            const float4 v = *reinterpret_cast<const float4*>(
                hb + (size_t)(unsigned)sj * 16 + fq * 4);
            acc.x = fmaf(w, v.x, acc.x);
            acc.y = fmaf(w, v.y, acc.y);
            acc.z = fmaf(w, v.z, acc.z);
            acc.w = fmaf(w, v.w, acc.w);
        }
        // butterfly-reduce across the 16 edge slots (lane strides 4,8,16,32)
        #pragma unroll
        for (int off = 4; off <= 32; off <<= 1) {
            acc.x += __shfl_xor(acc.x, off);
            acc.y += __shfl_xor(acc.y, off);
            acc.z += __shfl_xor(acc.z, off);
            acc.w += __shfl_xor(acc.w, off);
        }
        if (eslot == 0) {
            const float is = invS[node];               // 0 for deg-0 -> out = bias
            float4 r;
            r.x = fmaf(acc.x, is, b4.x);
            r.y = fmaf(acc.y, is, b4.y);
            r.z = fmaf(acc.z, is, b4.z);
            r.w = fmaf(acc.w, is, b4.w);
            *reinterpret_cast<float4*>(OUT + (size_t)node * 128 + chunk * 16 + fq * 4) = r;
        }
    }
}

// ---------------------------------------------------------------------------
__global__ void graph_ranges_kernel(const int* __restrict__ batch, int n_nodes,
                                    int n_graphs, int* __restrict__ gstart) {
    int g = blockIdx.x * blockDim.x + threadIdx.x;
    if (g > n_graphs) return;
    int lo = 0, hi = n_nodes;
    while (lo < hi) {
        int mid = (lo + hi) >> 1;
        if (batch[mid] < g) lo = mid + 1; else hi = mid;
    }
    gstart[g] = lo;
}

__global__ __launch_bounds__(128) void pool_linear_kernel(
    const float* __restrict__ X, const int* __restrict__ gstart,
    const float* __restrict__ lin_w, const float* __restrict__ lin_b,
    float* __restrict__ out)
{
    int g = blockIdx.x;
    int c = threadIdx.x;   // 0..127
    int s = gstart[g], e = gstart[g + 1];
    float acc = 0.f;
    for (int i = s; i < e; ++i) acc += X[(size_t)i * 128 + c];
    float cnt = (float)(e - s);
    float pooled = acc / fmaxf(cnt, 1.0f);
    __shared__ float p[128];
    p[c] = pooled;
    __syncthreads();
    if (c < 8) {
        float o = lin_b[c];
        for (int k = 0; k < 128; ++k) o += p[k] * lin_w[k * 8 + c];
        out[g * 8 + c] = o;
    }
}

// ---------------------------------------------------------------------------
extern "C" void kernel_launch(void* const* d_in, const int* in_sizes, int n_in,
                              void* d_out, int out_size, void* d_ws, size_t ws_size,
                              hipStream_t stream)
{
    const float* x     = (const float*)d_in[0];
    const int*   ei    = (const int*)d_in[1];
    const int*   batch = (const int*)d_in[3];
    const float* W[3]   = {(const float*)d_in[4],  (const float*)d_in[8],  (const float*)d_in[12]};
    const float* asr[3] = {(const float*)d_in[5],  (const float*)d_in[9],  (const float*)d_in[13]};
    const float* adt[3] = {(const float*)d_in[6],  (const float*)d_in[10], (const float*)d_in[14]};
    const float* bia[3] = {(const float*)d_in[7],  (const float*)d_in[11], (const float*)d_in[15]};
    const float* lin_w = (const float*)d_in[16];
    const float* lin_b = (const float*)d_in[17];
    float* out = (float*)d_out;

    char* ws = (char*)d_ws;
    size_t off = 0;
    auto carve = [&](size_t bytes) {
        void* p = ws + off;
        off = (off + bytes + 255) & ~(size_t)255;
        return p;
    };
    float* bufA     = (float*)carve((size_t)N_NODES_C * 128 * 4);  // Hc (chunked)
    float* bufB     = (float*)carve((size_t)N_NODES_C * 128 * 4);  // layer out / next x
    float* alpha_s  = (float*)carve((size_t)N_NODES_C * 4);
    float* alpha_d  = (float*)carve((size_t)N_NODES_C * 4);
    float* invS     = (float*)carve((size_t)N_NODES_C * 4);
    int*   deg      = (int*)carve((size_t)N_NODES_C * 4);
    int*   row_start= (int*)carve((size_t)(N_NODES_C + 1) * 4);
    int*   cursor   = (int*)carve((size_t)N_NODES_C * 4);
    int*   csr_src  = (int*)carve((size_t)N_EDGES_C * 4);
    long long* edge_sw = (long long*)carve((size_t)N_EDGES_C * 8);
    int*   gstart   = (int*)carve((size_t)(N_GRAPHS_C + 1) * 4);
    int*   bsum     = (int*)carve((size_t)SCAN_NB * 4);

    const int* src = ei;             // edge_index[0]
    const int* dst = ei + N_EDGES_C; // edge_index[1]

    // --- CSR build (graph identical across layers) ---
    (void)hipMemsetAsync(deg, 0, (size_t)N_NODES_C * 4, stream);
    hist_kernel<<<(N_EDGES_C + 255) / 256, 256, 0, stream>>>(dst, deg, N_EDGES_C);
    scan1_kernel<<<SCAN_NB, 256, 0, stream>>>(deg, bsum, N_NODES_C);
    scan2_kernel<<<1, 256, 0, stream>>>(bsum, SCAN_NB);
    scan3_kernel<<<SCAN_NB, 256, 0, stream>>>(deg, bsum, row_start, cursor, N_NODES_C);
    scatter_kernel<<<(N_EDGES_C + 255) / 256, 256, 0, stream>>>(src, dst, N_EDGES_C,
                                                                cursor, csr_src);
    graph_ranges_kernel<<<2, 256, 0, stream>>>(batch, N_NODES_C, N_GRAPHS_C, gstart);

    const int gemm_grid = (N_NODES_C + 63) / 64;
    const int wgt_grid  = (N_NODES_C + 3) / 4;          // wave per node
    const int agg_grid  = AGG_NODE_BLOCKS * N_CHUNKS;   // chunk = blockIdx & 7

    for (int l = 0; l < 3; ++l) {
        const float* xin = (l == 0) ? x : bufB;
        if (l == 0)
            gemm_alpha_kernel<IN_F_C><<<gemm_grid, 256, 0, stream>>>(
                xin, W[l], asr[l], adt[l], bufA, alpha_s, alpha_d, N_NODES_C, 0);
        else
            gemm_alpha_kernel<HID_C><<<gemm_grid, 256, 0, stream>>>(
                xin, W[l], asr[l], adt[l], bufA, alpha_s, alpha_d, N_NODES_C, 1);
        edge_weight_kernel<<<wgt_grid, 256, 0, stream>>>(
            alpha_s, alpha_d, row_start, csr_src, edge_sw, invS, N_NODES_C);
        agg_chunk_kernel<<<agg_grid, 256, 0, stream>>>(
            bufA, edge_sw, row_start, invS, bia[l], bufB);
    }

    // --- mean pool + linear ---
    pool_linear_kernel<<<N_GRAPHS_C, 128, 0, stream>>>(bufB, gstart, lin_w, lin_b, out);
}

// Round 7
// 665.135 us; speedup vs baseline: 1.6806x; 1.0865x over previous
//
#include <hip/hip_runtime.h>
#include <cstdint>
#include <cstddef>

#define N_NODES_C  50000
#define N_EDGES_C  800000
#define IN_F_C     256
#define HID_C      128
#define N_GRAPHS_C 256
#define NEG_SLOPE_C 0.2f
#define SCAN_NB    ((N_NODES_C + 255) / 256)   // 196 blocks
#define N_CHUNKS   8                            // 128 feats = 8 x 16
// 16 nodes per block (4 waves x 4 nodes); 50000/16 = 3125 exactly
#define AGG_NODE_BLOCKS (N_NODES_C / 16)

// ---------------------------------------------------------------------------
// CSR build: histogram of dst -> hierarchical exclusive scan -> scatter
// ---------------------------------------------------------------------------
__global__ void hist_kernel(const int* __restrict__ dst, int* __restrict__ deg, int E) {
    int e = blockIdx.x * blockDim.x + threadIdx.x;
    if (e < E) atomicAdd(&deg[dst[e]], 1);
}

__global__ __launch_bounds__(256) void scan1_kernel(const int* __restrict__ deg,
                                                    int* __restrict__ bsum, int n) {
    int i = blockIdx.x * 256 + threadIdx.x;
    int lane = threadIdx.x & 63;
    int w = threadIdx.x >> 6;
    int v = (i < n) ? deg[i] : 0;
    #pragma unroll
    for (int off = 32; off >= 1; off >>= 1) v += __shfl_xor(v, off);
    __shared__ int ws_[4];
    if (lane == 0) ws_[w] = v;
    __syncthreads();
    if (threadIdx.x == 0) bsum[blockIdx.x] = ws_[0] + ws_[1] + ws_[2] + ws_[3];
}

__global__ __launch_bounds__(256) void scan2_kernel(int* __restrict__ bsum, int nb) {
    int t = threadIdx.x;
    int lane = t & 63;
    int w = t >> 6;
    int orig = (t < nb) ? bsum[t] : 0;
    int v = orig;
    #pragma unroll
    for (int off = 1; off < 64; off <<= 1) {
        int u = __shfl_up(v, off);
        if (lane >= off) v += u;
    }
    __shared__ int wsum[4];
    if (lane == 63) wsum[w] = v;
    __syncthreads();
    int add = 0;
    for (int i = 0; i < w; ++i) add += wsum[i];
    if (t < nb) bsum[t] = v + add - orig;   // exclusive prefix
}

__global__ __launch_bounds__(256) void scan3_kernel(const int* __restrict__ deg,
                                                    const int* __restrict__ boff,
                                                    int* __restrict__ row_start,
                                                    int* __restrict__ cursor, int n) {
    int i = blockIdx.x * 256 + threadIdx.x;
    int lane = threadIdx.x & 63;
    int w = threadIdx.x >> 6;
    int d = (i < n) ? deg[i] : 0;
    int v = d;
    #pragma unroll
    for (int off = 1; off < 64; off <<= 1) {
        int u = __shfl_up(v, off);
        if (lane >= off) v += u;
    }
    __shared__ int wsum[4];
    if (lane == 63) wsum[w] = v;
    __syncthreads();
    int add = boff[blockIdx.x];
    for (int k = 0; k < w; ++k) add += wsum[k];
    int excl = v - d + add;
    if (i < n) {
        row_start[i] = excl;
        cursor[i] = excl;
        if (i == n - 1) row_start[n] = excl + d;
    }
}

__global__ void scatter_kernel(const int* __restrict__ src, const int* __restrict__ dst, int E,
                               int* __restrict__ cursor, int* __restrict__ csr_src) {
    int e = blockIdx.x * blockDim.x + threadIdx.x;
    if (e < E) {
        int pos = atomicAdd(&cursor[dst[e]], 1);
        csr_src[pos] = src[e];
    }
}

// ---------------------------------------------------------------------------
// GEMM (fp32, vector ALU): Hc = act(X) @ W written in CHUNKED layout
// Hc[chunk][node][16], chunk = col/16. Fused alpha_s/alpha_d dots.
// ---------------------------------------------------------------------------
template <int K>
__global__ __launch_bounds__(256) void gemm_alpha_kernel(
    const float* __restrict__ X, const float* __restrict__ W,
    const float* __restrict__ a_src, const float* __restrict__ a_dst,
    float* __restrict__ Hc, float* __restrict__ alpha_s, float* __restrict__ alpha_d,
    int n_rows, int do_relu)
{
    constexpr int KT = 32;
    __shared__ float Xs[64 * KT];     // 8 KiB
    __shared__ float Ws[KT * 128];    // 16 KiB

    const int t = threadIdx.x;
    const int row0 = blockIdx.x * 64;
    const int j = t & 31;             // col group: cols 4j..4j+3
    const int rg = t >> 5;            // row group: rows 8rg..8rg+7

    float acc[8][4];
    #pragma unroll
    for (int i = 0; i < 8; ++i)
        #pragma unroll
        for (int c = 0; c < 4; ++c) acc[i][c] = 0.f;

    for (int k0 = 0; k0 < K; k0 += KT) {
        __syncthreads();
        #pragma unroll
        for (int it = 0; it < 2; ++it) {
            int fi = t + it * 256;
            int r = fi >> 3;
            int c4 = (fi & 7) << 2;
            int grow = row0 + r;
            float4 v = make_float4(0.f, 0.f, 0.f, 0.f);
            if (grow < n_rows) {
                v = *reinterpret_cast<const float4*>(X + (size_t)grow * K + k0 + c4);
                if (do_relu) {
                    v.x = fmaxf(v.x, 0.f); v.y = fmaxf(v.y, 0.f);
                    v.z = fmaxf(v.z, 0.f); v.w = fmaxf(v.w, 0.f);
                }
            }
            *reinterpret_cast<float4*>(&Xs[r * KT + c4]) = v;
        }
        #pragma unroll
        for (int it = 0; it < 4; ++it) {
            int fi = t + it * 256;
            int kk = fi >> 5;
            int c4 = (fi & 31) << 2;
            float4 v = *reinterpret_cast<const float4*>(W + (size_t)(k0 + kk) * 128 + c4);
            *reinterpret_cast<float4*>(&Ws[kk * 128 + c4]) = v;
        }
        __syncthreads();
        #pragma unroll
        for (int kk = 0; kk < KT; kk += 4) {
            float4 wv[4];
            #pragma unroll
            for (int c = 0; c < 4; ++c)
                wv[c] = *reinterpret_cast<const float4*>(&Ws[(kk + c) * 128 + (j << 2)]);
            #pragma unroll
            for (int i = 0; i < 8; ++i) {
                float4 xv = *reinterpret_cast<const float4*>(&Xs[(rg * 8 + i) * KT + kk]);
                acc[i][0] = fmaf(xv.x, wv[0].x, acc[i][0]);
                acc[i][1] = fmaf(xv.x, wv[0].y, acc[i][1]);
                acc[i][2] = fmaf(xv.x, wv[0].z, acc[i][2]);
                acc[i][3] = fmaf(xv.x, wv[0].w, acc[i][3]);
                acc[i][0] = fmaf(xv.y, wv[1].x, acc[i][0]);
                acc[i][1] = fmaf(xv.y, wv[1].y, acc[i][1]);
                acc[i][2] = fmaf(xv.y, wv[1].z, acc[i][2]);
                acc[i][3] = fmaf(xv.y, wv[1].w, acc[i][3]);
                acc[i][0] = fmaf(xv.z, wv[2].x, acc[i][0]);
                acc[i][1] = fmaf(xv.z, wv[2].y, acc[i][1]);
                acc[i][2] = fmaf(xv.z, wv[2].z, acc[i][2]);
                acc[i][3] = fmaf(xv.z, wv[2].w, acc[i][3]);
                acc[i][0] = fmaf(xv.w, wv[3].x, acc[i][0]);
                acc[i][1] = fmaf(xv.w, wv[3].y, acc[i][1]);
                acc[i][2] = fmaf(xv.w, wv[3].z, acc[i][2]);
                acc[i][3] = fmaf(xv.w, wv[3].w, acc[i][3]);
            }
        }
    }

    float4 as4 = *reinterpret_cast<const float4*>(a_src + (j << 2));
    float4 ad4 = *reinterpret_cast<const float4*>(a_dst + (j << 2));
    const int chunk = j >> 2;          // col/16
    const int within = (j << 2) & 15;  // 0,4,8,12
    #pragma unroll
    for (int i = 0; i < 8; ++i) {
        int grow = row0 + rg * 8 + i;
        float s = acc[i][0] * as4.x + acc[i][1] * as4.y + acc[i][2] * as4.z + acc[i][3] * as4.w;
        float d = acc[i][0] * ad4.x + acc[i][1] * ad4.y + acc[i][2] * ad4.z + acc[i][3] * ad4.w;
        #pragma unroll
        for (int off = 16; off >= 1; off >>= 1) {
            s += __shfl_xor(s, off);
            d += __shfl_xor(d, off);
        }
        if (grow < n_rows) {
            *reinterpret_cast<float4*>(Hc + ((size_t)chunk * N_NODES_C + grow) * 16 + within) =
                make_float4(acc[i][0], acc[i][1], acc[i][2], acc[i][3]);
            if (j == 0) { alpha_s[grow] = s; alpha_d[grow] = d; }
        }
    }
}

// ---------------------------------------------------------------------------
// Pass A: per-edge unnormalized softmax weight + per-dst 1/S.
// One wave per dst node. Stores (src, w) packed 8B per edge as long long.
// ---------------------------------------------------------------------------
__global__ __launch_bounds__(256) void edge_weight_kernel(
    const float* __restrict__ alpha_s, const float* __restrict__ alpha_d,
    const int* __restrict__ row_start, const int* __restrict__ csr_src,
    long long* __restrict__ edge_sw, float* __restrict__ invS, int n_nodes)
{
    int wid = (blockIdx.x * blockDim.x + threadIdx.x) >> 6;
    int lane = threadIdx.x & 63;
    if (wid >= n_nodes) return;

    int e0 = row_start[wid], e1 = row_start[wid + 1];
    float ad = alpha_d[wid];

    float S = 0.f;
    for (int base = e0; base < e1; base += 64) {
        int e = base + lane;
        float w = 0.f;
        if (e < e1) {
            int s = csr_src[e];
            float z = alpha_s[s] + ad;
            z = (z >= 0.f) ? z : NEG_SLOPE_C * z;
            w = __expf(z);
            long long p = ((long long)__float_as_int(w) << 32) |
                          (unsigned int)s;
            edge_sw[e] = p;
        }
        float ws = w;
        #pragma unroll
        for (int off = 32; off >= 1; off >>= 1) ws += __shfl_xor(ws, off);
        S += ws;
    }
    if (lane == 0) invS[wid] = (e1 > e0) ? (1.f / S) : 0.f;
}

// ---------------------------------------------------------------------------
// Pass B: chunked weighted gather. chunk = blockIdx & 7 pins each 3.2 MB
// H-chunk to one XCD's L2 (perf heuristic only).
// Lane owns one (node, feature): wave = 4 nodes x 16 features. Each lane
// loops its node's edges: edge_sw[e] is a 16-lane broadcast load, the H
// gather reads 64 B per node-group (4 segments/instr), 1 FMA per edge.
// NO cross-lane reduction at all. Unroll x4 for memory-level parallelism.
// 50000 nodes = 3125 blocks x 16 nodes exactly: no bounds checks.
// ---------------------------------------------------------------------------
__global__ __launch_bounds__(256) void agg_chunk_kernel(
    const float* __restrict__ Hc, const long long* __restrict__ edge_sw,
    const int* __restrict__ row_start, const float* __restrict__ invS,
    const float* __restrict__ bias, float* __restrict__ OUT)
{
    const int chunk = blockIdx.x & 7;
    const int t = threadIdx.x;
    const int node = (blockIdx.x >> 3) * 16 + (t >> 6) * 4 + ((t & 63) >> 4);
    const int f = t & 15;               // feature within chunk

    const int e0 = row_start[node], e1 = row_start[node + 1];
    const float* __restrict__ hb = Hc + (size_t)chunk * N_NODES_C * 16;

    float a0 = 0.f, a1 = 0.f, a2 = 0.f, a3 = 0.f;
    int e = e0;
    for (; e + 4 <= e1; e += 4) {
        const long long p0 = edge_sw[e];
        const long long p1 = edge_sw[e + 1];
        const long long p2 = edge_sw[e + 2];
        const long long p3 = edge_sw[e + 3];
        const float v0 = hb[(size_t)(unsigned)(int)p0 * 16 + f];
        const float v1 = hb[(size_t)(unsigned)(int)p1 * 16 + f];
        const float v2 = hb[(size_t)(unsigned)(int)p2 * 16 + f];
        const float v3 = hb[(size_t)(unsigned)(int)p3 * 16 + f];
        a0 = fmaf(__int_as_float((int)(p0 >> 32)), v0, a0);
        a1 = fmaf(__int_as_float((int)(p1 >> 32)), v1, a1);
        a2 = fmaf(__int_as_float((int)(p2 >> 32)), v2, a2);
        a3 = fmaf(__int_as_float((int)(p3 >> 32)), v3, a3);
    }
    for (; e < e1; ++e) {
        const long long p = edge_sw[e];
        const float v = hb[(size_t)(unsigned)(int)p * 16 + f];
        a0 = fmaf(__int_as_float((int)(p >> 32)), v, a0);
    }
    const float acc = (a0 + a1) + (a2 + a3);
    // invS = 0 for deg-0 nodes -> out = bias
    const float r = fmaf(acc, invS[node], bias[chunk * 16 + f]);
    OUT[(size_t)node * 128 + chunk * 16 + f] = r;
}

// ---------------------------------------------------------------------------
__global__ void graph_ranges_kernel(const int* __restrict__ batch, int n_nodes,
                                    int n_graphs, int* __restrict__ gstart) {
    int g = blockIdx.x * blockDim.x + threadIdx.x;
    if (g > n_graphs) return;
    int lo = 0, hi = n_nodes;
    while (lo < hi) {
        int mid = (lo + hi) >> 1;
        if (batch[mid] < g) lo = mid + 1; else hi = mid;
    }
    gstart[g] = lo;
}

__global__ __launch_bounds__(128) void pool_linear_kernel(
    const float* __restrict__ X, const int* __restrict__ gstart,
    const float* __restrict__ lin_w, const float* __restrict__ lin_b,
    float* __restrict__ out)
{
    int g = blockIdx.x;
    int c = threadIdx.x;   // 0..127
    int s = gstart[g], e = gstart[g + 1];
    float acc = 0.f;
    for (int i = s; i < e; ++i) acc += X[(size_t)i * 128 + c];
    float cnt = (float)(e - s);
    float pooled = acc / fmaxf(cnt, 1.0f);
    __shared__ float p[128];
    p[c] = pooled;
    __syncthreads();
    if (c < 8) {
        float o = lin_b[c];
        for (int k = 0; k < 128; ++k) o += p[k] * lin_w[k * 8 + c];
        out[g * 8 + c] = o;
    }
}

// ---------------------------------------------------------------------------
extern "C" void kernel_launch(void* const* d_in, const int* in_sizes, int n_in,
                              void* d_out, int out_size, void* d_ws, size_t ws_size,
                              hipStream_t stream)
{
    const float* x     = (const float*)d_in[0];
    const int*   ei    = (const int*)d_in[1];
    const int*   batch = (const int*)d_in[3];
    const float* W[3]   = {(const float*)d_in[4],  (const float*)d_in[8],  (const float*)d_in[12]};
    const float* asr[3] = {(const float*)d_in[5],  (const float*)d_in[9],  (const float*)d_in[13]};
    const float* adt[3] = {(const float*)d_in[6],  (const float*)d_in[10], (const float*)d_in[14]};
    const float* bia[3] = {(const float*)d_in[7],  (const float*)d_in[11], (const float*)d_in[15]};
    const float* lin_w = (const float*)d_in[16];
    const float* lin_b = (const float*)d_in[17];
    float* out = (float*)d_out;

    char* ws = (char*)d_ws;
    size_t off = 0;
    auto carve = [&](size_t bytes) {
        void* p = ws + off;
        off = (off + bytes + 255) & ~(size_t)255;
        return p;
    };
    float* bufA     = (float*)carve((size_t)N_NODES_C * 128 * 4);  // Hc (chunked)
    float* bufB     = (float*)carve((size_t)N_NODES_C * 128 * 4);  // layer out / next x
    float* alpha_s  = (float*)carve((size_t)N_NODES_C * 4);
    float* alpha_d  = (float*)carve((size_t)N_NODES_C * 4);
    float* invS     = (float*)carve((size_t)N_NODES_C * 4);
    int*   deg      = (int*)carve((size_t)N_NODES_C * 4);
    int*   row_start= (int*)carve((size_t)(N_NODES_C + 1) * 4);
    int*   cursor   = (int*)carve((size_t)N_NODES_C * 4);
    int*   csr_src  = (int*)carve((size_t)N_EDGES_C * 4);
    long long* edge_sw = (long long*)carve((size_t)N_EDGES_C * 8);
    int*   gstart   = (int*)carve((size_t)(N_GRAPHS_C + 1) * 4);
    int*   bsum     = (int*)carve((size_t)SCAN_NB * 4);

    const int* src = ei;             // edge_index[0]
    const int* dst = ei + N_EDGES_C; // edge_index[1]

    // --- CSR build (graph identical across layers) ---
    (void)hipMemsetAsync(deg, 0, (size_t)N_NODES_C * 4, stream);
    hist_kernel<<<(N_EDGES_C + 255) / 256, 256, 0, stream>>>(dst, deg, N_EDGES_C);
    scan1_kernel<<<SCAN_NB, 256, 0, stream>>>(deg, bsum, N_NODES_C);
    scan2_kernel<<<1, 256, 0, stream>>>(bsum, SCAN_NB);
    scan3_kernel<<<SCAN_NB, 256, 0, stream>>>(deg, bsum, row_start, cursor, N_NODES_C);
    scatter_kernel<<<(N_EDGES_C + 255) / 256, 256, 0, stream>>>(src, dst, N_EDGES_C,
                                                                cursor, csr_src);
    graph_ranges_kernel<<<2, 256, 0, stream>>>(batch, N_NODES_C, N_GRAPHS_C, gstart);

    const int gemm_grid = (N_NODES_C + 63) / 64;
    const int wgt_grid  = (N_NODES_C + 3) / 4;          // wave per node
    const int agg_grid  = AGG_NODE_BLOCKS * N_CHUNKS;   // chunk = blockIdx & 7

    for (int l = 0; l < 3; ++l) {
        const float* xin = (l == 0) ? x : bufB;
        if (l == 0)
            gemm_alpha_kernel<IN_F_C><<<gemm_grid, 256, 0, stream>>>(
                xin, W[l], asr[l], adt[l], bufA, alpha_s, alpha_d, N_NODES_C, 0);
        else
            gemm_alpha_kernel<HID_C><<<gemm_grid, 256, 0, stream>>>(
                xin, W[l], asr[l], adt[l], bufA, alpha_s, alpha_d, N_NODES_C, 1);
        edge_weight_kernel<<<wgt_grid, 256, 0, stream>>>(
            alpha_s, alpha_d, row_start, csr_src, edge_sw, invS, N_NODES_C);
        agg_chunk_kernel<<<agg_grid, 256, 0, stream>>>(
            bufA, edge_sw, row_start, invS, bia[l], bufB);
    }

    // --- mean pool + linear ---
    pool_linear_kernel<<<N_GRAPHS_C, 128, 0, stream>>>(bufB, gstart, lin_w, lin_b, out);
}